// Round 6
// baseline (60.243 us; speedup 1.0000x reference)
//
#include <hip/hip_runtime.h>

#define NUM_CATEGORIES 64
#define IN_DIM 1024
#define OUT_DIM 1024
#define BATCH 32
#define SEQ 512

#define BM 256
#define BN 256
#define BK 64
#define NSTEP (IN_DIM / BK)   // 16

#define LDA 72     // bf16 elems per A row (128B data + 16B pad); 144 ≡ 16 mod 128
#define LDBW 260   // u32 words per B k-pair row (256 data + 4 pad)

typedef float f32x4 __attribute__((ext_vector_type(4)));
typedef unsigned int u32x2 __attribute__((ext_vector_type(2)));
typedef unsigned int u32x4 __attribute__((ext_vector_type(4)));
typedef __bf16 bf16x8 __attribute__((ext_vector_type(8)));

__device__ inline unsigned int f2bf_rne(float f) {
    unsigned int u = __builtin_bit_cast(unsigned int, f);
    return (u + 0x7FFFu + ((u >> 16) & 1u)) >> 16;
}
__device__ inline unsigned int pack2(float lo, float hi) {
    return f2bf_rne(lo) | (f2bf_rne(hi) << 16);
}

__global__ __launch_bounds__(512, 2)
void cslinear_kernel(const float* __restrict__ x,
                     const int* __restrict__ cid,
                     const float* __restrict__ weight,
                     const float* __restrict__ bias,
                     float* __restrict__ out) {
    // A: [m][k] bf16 (padded rows). B: u32 k-pair words [kp][n] (padded).
    __shared__ unsigned short As[2][BM * LDA];          // 2 x 36 KB
    __shared__ unsigned int   Bs[2][(BK / 2) * LDBW];   // 2 x 32.5 KB   (total 137 KB)

    const int t    = threadIdx.x;
    const int lane = t & 63;
    const int w    = t >> 6;      // 0..7

    // XCD-aware remap: slot s -> XCD s%8; each XCD owns 4 whole batches
    // (8 blocks each) so x re-reads (x4) and W re-reads (x2) hit its L2.
    const int s    = blockIdx.x;      // 0..255
    const int xcd  = s & 7;
    const int ixd  = s >> 3;          // 0..31
    const int b    = xcd + 8 * (ixd >> 3);
    const int j    = ixd & 7;
    const int nt   = j & 3;           // 0..3
    const int mt   = j >> 2;          // 0..1

    const int c = cid[b];
    const float* Wp = weight + (size_t)c * IN_DIM * OUT_DIM + (size_t)nt * BN;
    const float* Xp = x + ((size_t)b * SEQ + (size_t)mt * BM) * IN_DIM;
    float* Op = out + ((size_t)b * SEQ + (size_t)mt * BM) * OUT_DIM + (size_t)nt * BN;

    f32x4 acc[8][4] = {};         // wave tile 128(m) x 64(n)

    const int mbase = (w >> 2) * 128;   // 0 or 128
    const int nbase = (w & 3) * 64;     // 0,64,128,192
    const int lrow  = lane & 15;
    const int lhi   = lane >> 4;        // 0..3

    // 1-deep staging registers (static indices only — rule #20)
    f32x4 ra[8];                  // A: 256x64 f32 / 512thr = 8 x f32x4
    f32x4 rb0[4], rb1[4];         // B: 64x256 f32 / 512thr = 4 units x 2 rows

    auto LOADT = [&](int ks) {
        const float* Xk = Xp + ks * BK;
        #pragma unroll
        for (int i = 0; i < 8; ++i) {
            int f   = i * 512 + t;        // 0..4095
            int row = f >> 4;             // 0..255
            int c4  = f & 15;             // 0..15
            ra[i] = *reinterpret_cast<const f32x4*>(Xk + (size_t)row * IN_DIM + c4 * 4);
        }
        const float* Wk = Wp + (size_t)(ks * BK) * OUT_DIM;
        #pragma unroll
        for (int i = 0; i < 4; ++i) {
            int u  = i * 512 + t;         // 0..2047
            int kp = u >> 6;              // 0..31
            int n4 = u & 63;              // 0..63
            const float* bse = Wk + (size_t)(2 * kp) * OUT_DIM + n4 * 4;
            rb0[i] = *reinterpret_cast<const f32x4*>(bse);
            rb1[i] = *reinterpret_cast<const f32x4*>(bse + OUT_DIM);
        }
    };

    auto STORET = [&](int p) {
        char* AsB = reinterpret_cast<char*>(&As[p][0]);
        #pragma unroll
        for (int i = 0; i < 8; ++i) {
            int f   = i * 512 + t;
            int row = f >> 4;
            int c4  = f & 15;
            u32x2 q;
            q.x = pack2(ra[i].x, ra[i].y);
            q.y = pack2(ra[i].z, ra[i].w);
            *reinterpret_cast<u32x2*>(AsB + row * (LDA * 2) + c4 * 8) = q;
        }
        unsigned int* BsW = &Bs[p][0];
        #pragma unroll
        for (int i = 0; i < 4; ++i) {
            int u  = i * 512 + t;
            int kp = u >> 6;
            int n4 = u & 63;
            u32x4 q;
            #pragma unroll
            for (int jj = 0; jj < 4; ++jj)
                q[jj] = pack2(rb0[i][jj], rb1[i][jj]);
            *reinterpret_cast<u32x4*>(BsW + kp * LDBW + n4 * 4) = q;  // contiguous b128
        }
    };

    LOADT(0);

    for (int ks = 0; ks < NSTEP; ++ks) {
        const int p = ks & 1;

        STORET(p);                          // counted vmcnt waits on staged regs
        if (ks + 1 < NSTEP) LOADT(ks + 1);  // refill same regs; WAR keeps order,
                                            // loads fly across barrier + compute

        asm volatile("s_waitcnt lgkmcnt(0)" ::: "memory");
        __builtin_amdgcn_s_barrier();
        __builtin_amdgcn_sched_barrier(0);

        const char* AsB = reinterpret_cast<const char*>(&As[p][0]);
        const unsigned int* BsW = &Bs[p][0];

        // two k-chunks of 32 per step
        #pragma unroll
        for (int kk = 0; kk < 2; ++kk) {
            bf16x8 bfr[4];
            #pragma unroll
            for (int ni = 0; ni < 4; ++ni) {
                int n   = nbase + ni * 16 + lrow;
                int kp0 = kk * 16 + lhi * 4;
                u32x4 wds;
                #pragma unroll
                for (int jj = 0; jj < 4; ++jj)
                    wds[jj] = BsW[(kp0 + jj) * LDBW + n];
                bfr[ni] = __builtin_bit_cast(bf16x8, wds);
            }
            #pragma unroll
            for (int mi = 0; mi < 8; ++mi) {
                int r = mbase + mi * 16 + lrow;
                bf16x8 afr = *reinterpret_cast<const bf16x8*>(
                    AsB + r * (LDA * 2) + kk * 64 + lhi * 16);
                #pragma unroll
                for (int ni = 0; ni < 4; ++ni)
                    acc[mi][ni] = __builtin_amdgcn_mfma_f32_16x16x32_bf16(
                        afr, bfr[ni], acc[mi][ni], 0, 0, 0);
            }
        }
        // double buffer + one barrier/step: LDS[p] is next written at step
        // ks+2, and every wave's step-ks reads completed (lgkmcnt-ordered
        // before its MFMAs) before it reaches barrier ks+1.
    }

    // epilogue: C/D layout col=lane&15, row=(lane>>4)*4+reg
    const int lcol  = lane & 15;
    const int lrow4 = (lane >> 4) * 4;
    float bv[4];
    #pragma unroll
    for (int ni = 0; ni < 4; ++ni)
        bv[ni] = bias[(size_t)c * OUT_DIM + nt * BN + nbase + ni * 16 + lcol];

    #pragma unroll
    for (int mi = 0; mi < 8; ++mi) {
        int rbase = mbase + mi * 16 + lrow4;
        #pragma unroll
        for (int ni = 0; ni < 4; ++ni) {
            int ncol = nbase + ni * 16 + lcol;
            #pragma unroll
            for (int r = 0; r < 4; ++r) {
                Op[(size_t)(rbase + r) * OUT_DIM + ncol] = acc[mi][ni][r] + bv[ni];
            }
        }
    }
}

extern "C" void kernel_launch(void* const* d_in, const int* in_sizes, int n_in,
                              void* d_out, int out_size, void* d_ws, size_t ws_size,
                              hipStream_t stream) {
    const float* x      = (const float*)d_in[0];
    const int*   cid    = (const int*)d_in[1];
    const float* weight = (const float*)d_in[2];
    const float* bias   = (const float*)d_in[3];
    float* out = (float*)d_out;

    dim3 grid(256);     // flat: XCD-aware remap inside kernel
    dim3 block(512);
    hipLaunchKernelGGL(cslinear_kernel, grid, block, 0, stream,
                       x, cid, weight, bias, out);
}

// Round 7
// 60.045 us; speedup vs baseline: 1.0033x; 1.0033x over previous
//
#include <hip/hip_runtime.h>

#define NUM_CATEGORIES 64
#define IN_DIM 1024
#define OUT_DIM 1024
#define BATCH 32
#define SEQ 512

#define BM 256
#define BN 128
#define BK 32
#define NSTEP (IN_DIM / BK)   // 32

#define LDA 40     // bf16 elems per A row (64B data + 16B pad) -> 80 B row stride
#define LDBW 132   // u32 words per B k-pair row (128 data + 4 pad)

typedef float f32x4 __attribute__((ext_vector_type(4)));
typedef unsigned int u32x2 __attribute__((ext_vector_type(2)));
typedef unsigned int u32x4 __attribute__((ext_vector_type(4)));
typedef __bf16 bf16x8 __attribute__((ext_vector_type(8)));

__device__ inline unsigned int f2bf_rne(float f) {
    unsigned int u = __builtin_bit_cast(unsigned int, f);
    return (u + 0x7FFFu + ((u >> 16) & 1u)) >> 16;
}
__device__ inline unsigned int pack2(float lo, float hi) {
    return f2bf_rne(lo) | (f2bf_rne(hi) << 16);
}

// 256 threads (4 waves), 2 blocks/CU: independent barriers overlap each
// other's drain + epilogue (R6 showed lockstep 8-wave blocks leave pipes idle)
__global__ __launch_bounds__(256, 2)
void cslinear_kernel(const float* __restrict__ x,
                     const int* __restrict__ cid,
                     const float* __restrict__ weight,
                     const float* __restrict__ bias,
                     float* __restrict__ out) {
    __shared__ unsigned short As[2][BM * LDA];          // 2 x 20 KB
    __shared__ unsigned int   Bs[2][(BK / 2) * LDBW];   // 2 x 8.25 KB  (57 KB total)

    const int t    = threadIdx.x;
    const int lane = t & 63;
    const int w    = t >> 6;      // 0..3

    // XCD-aware remap: slot s -> XCD s%8; each XCD owns 4 whole batches
    // (16 blocks each, all co-resident on its 32 CUs at 2 blocks/CU).
    const int s    = blockIdx.x;      // 0..511
    const int xcd  = s & 7;
    const int ixd  = s >> 3;          // 0..63
    const int b    = xcd + 8 * (ixd >> 4);   // 4 batches per XCD
    const int j    = ixd & 15;        // 0..15 block within batch
    const int nt   = j & 7;           // 0..7
    const int mt   = j >> 3;          // 0..1

    const int c = cid[b];
    const float* Wp = weight + (size_t)c * IN_DIM * OUT_DIM + (size_t)nt * BN;
    const float* Xp = x + ((size_t)b * SEQ + (size_t)mt * BM) * IN_DIM;
    float* Op = out + ((size_t)b * SEQ + (size_t)mt * BM) * OUT_DIM + (size_t)nt * BN;

    f32x4 acc[8][4] = {};               // wave tile 128(m) x 64(n)

    const int mbase = (w >> 1) * 128;   // 0 or 128
    const int nbase = (w & 1) * 64;     // 0 or 64
    const int lrow  = lane & 15;
    const int lhi   = lane >> 4;        // 0..3

    // 1-deep staging registers (static indices only — rule #20)
    f32x4 ra[8];              // A: 256x32 f32 / 256 thr = 8 x f32x4
    f32x4 rb0[2], rb1[2];     // B: 32x128 f32 / 256 thr = 2 units x 2 rows

    auto LOADT = [&](int ks) {
        const float* Xk = Xp + ks * BK;
        #pragma unroll
        for (int i = 0; i < 8; ++i) {
            int f   = i * 256 + t;        // 0..2047
            int row = f >> 3;             // 0..255
            int c4  = f & 7;              // 0..7
            ra[i] = *reinterpret_cast<const f32x4*>(Xk + (size_t)row * IN_DIM + c4 * 4);
        }
        const float* Wk = Wp + (size_t)(ks * BK) * OUT_DIM;
        #pragma unroll
        for (int i = 0; i < 2; ++i) {
            int u  = i * 256 + t;         // 0..511
            int kp = u >> 5;              // 0..15
            int n4 = u & 31;              // 0..31
            const float* bse = Wk + (size_t)(2 * kp) * OUT_DIM + n4 * 4;
            rb0[i] = *reinterpret_cast<const f32x4*>(bse);
            rb1[i] = *reinterpret_cast<const f32x4*>(bse + OUT_DIM);
        }
    };

    auto STORET = [&](int p) {
        char* AsB = reinterpret_cast<char*>(&As[p][0]);
        #pragma unroll
        for (int i = 0; i < 8; ++i) {
            int f   = i * 256 + t;
            int row = f >> 3;
            int c4  = f & 7;
            u32x2 q;
            q.x = pack2(ra[i].x, ra[i].y);
            q.y = pack2(ra[i].z, ra[i].w);
            *reinterpret_cast<u32x2*>(AsB + row * (LDA * 2) + c4 * 8) = q;
        }
        unsigned int* BsW = &Bs[p][0];
        #pragma unroll
        for (int i = 0; i < 2; ++i) {
            int u  = i * 256 + t;
            int kp = u >> 5;
            int n4 = u & 31;
            u32x4 q;
            #pragma unroll
            for (int jj = 0; jj < 4; ++jj)
                q[jj] = pack2(rb0[i][jj], rb1[i][jj]);
            *reinterpret_cast<u32x4*>(BsW + kp * LDBW + n4 * 4) = q;  // contiguous b128
        }
    };

    LOADT(0);

    for (int ks = 0; ks < NSTEP; ++ks) {
        const int p = ks & 1;

        STORET(p);                          // counted vmcnt waits on staged regs
        if (ks + 1 < NSTEP) LOADT(ks + 1);  // next tile in flight across barrier

        asm volatile("s_waitcnt lgkmcnt(0)" ::: "memory");
        __builtin_amdgcn_s_barrier();
        __builtin_amdgcn_sched_barrier(0);

        const char* AsB = reinterpret_cast<const char*>(&As[p][0]);
        const unsigned int* BsW = &Bs[p][0];

        bf16x8 bfr[4];
        #pragma unroll
        for (int ni = 0; ni < 4; ++ni) {
            int n   = nbase + ni * 16 + lrow;
            int kp0 = lhi * 4;
            u32x4 wds;
            #pragma unroll
            for (int jj = 0; jj < 4; ++jj)
                wds[jj] = BsW[(kp0 + jj) * LDBW + n];
            bfr[ni] = __builtin_bit_cast(bf16x8, wds);
        }
        #pragma unroll
        for (int mi = 0; mi < 8; ++mi) {
            int r = mbase + mi * 16 + lrow;
            bf16x8 afr = *reinterpret_cast<const bf16x8*>(AsB + r * (LDA * 2) + lhi * 16);
            #pragma unroll
            for (int ni = 0; ni < 4; ++ni)
                acc[mi][ni] = __builtin_amdgcn_mfma_f32_16x16x32_bf16(
                    afr, bfr[ni], acc[mi][ni], 0, 0, 0);
        }
        // double buffer + one barrier/step: LDS[p] next written at step ks+2,
        // after barrier ks+1 has ordered all step-ks readers past it.
    }

    // epilogue: C/D layout col=lane&15, row=(lane>>4)*4+reg
    const int lcol  = lane & 15;
    const int lrow4 = (lane >> 4) * 4;
    float bv[4];
    #pragma unroll
    for (int ni = 0; ni < 4; ++ni)
        bv[ni] = bias[(size_t)c * OUT_DIM + nt * BN + nbase + ni * 16 + lcol];

    #pragma unroll
    for (int mi = 0; mi < 8; ++mi) {
        int rbase = mbase + mi * 16 + lrow4;
        #pragma unroll
        for (int ni = 0; ni < 4; ++ni) {
            int ncol = nbase + ni * 16 + lcol;
            #pragma unroll
            for (int r = 0; r < 4; ++r) {
                Op[(size_t)(rbase + r) * OUT_DIM + ncol] = acc[mi][ni][r] + bv[ni];
            }
        }
    }
}

extern "C" void kernel_launch(void* const* d_in, const int* in_sizes, int n_in,
                              void* d_out, int out_size, void* d_ws, size_t ws_size,
                              hipStream_t stream) {
    const float* x      = (const float*)d_in[0];
    const int*   cid    = (const int*)d_in[1];
    const float* weight = (const float*)d_in[2];
    const float* bias   = (const float*)d_in[3];
    float* out = (float*)d_out;

    dim3 grid(512);     // flat: XCD-aware remap inside kernel; 2 blocks/CU
    dim3 block(256);
    hipLaunchKernelGGL(cslinear_kernel, grid, block, 0, stream,
                       x, cid, weight, bias, out);
}

// Round 8
// 58.018 us; speedup vs baseline: 1.0384x; 1.0349x over previous
//
#include <hip/hip_runtime.h>
#include <type_traits>

#define NUM_CATEGORIES 64
#define IN_DIM 1024
#define OUT_DIM 1024
#define BATCH 32
#define SEQ 512

#define BM 256
#define BN 256
#define BK 32
#define NSTEP (IN_DIM / BK)   // 32

#define LDA 40     // bf16 elems per A row (64B data + 16B pad)
#define LDBW 260   // u32 words per B k-pair row (256 data + 4 pad)

typedef float f32x4 __attribute__((ext_vector_type(4)));
typedef unsigned int u32x2 __attribute__((ext_vector_type(2)));
typedef unsigned int u32x4 __attribute__((ext_vector_type(4)));
typedef __bf16 bf16x8 __attribute__((ext_vector_type(8)));

__device__ inline unsigned int f2bf_rne(float f) {
    unsigned int u = __builtin_bit_cast(unsigned int, f);
    return (u + 0x7FFFu + ((u >> 16) & 1u)) >> 16;
}
__device__ inline unsigned int pack2(float lo, float hi) {
    return f2bf_rne(lo) | (f2bf_rne(hi) << 16);
}

__global__ __launch_bounds__(512, 2)
void cslinear_kernel(const float* __restrict__ x,
                     const int* __restrict__ cid,
                     const float* __restrict__ weight,
                     const float* __restrict__ bias,
                     float* __restrict__ out) {
    __shared__ unsigned short As[2][BM * LDA];          // 2 x 20 KB
    __shared__ unsigned int   Bs[2][(BK / 2) * LDBW];   // 2 x 16.25 KB

    const int t    = threadIdx.x;
    const int lane = t & 63;
    const int w    = t >> 6;      // 0..7

    // XCD-aware remap: slot s -> XCD s%8; each XCD owns 4 whole batches.
    const int s    = blockIdx.x;      // 0..255
    const int xcd  = s & 7;
    const int ixd  = s >> 3;          // 0..31
    const int b    = xcd + 8 * (ixd >> 3);
    const int j    = ixd & 7;
    const int nt   = j & 3;           // 0..3
    const int mt   = j >> 2;          // 0..1

    const int c = cid[b];
    const float* Wp = weight + (size_t)c * IN_DIM * OUT_DIM + (size_t)nt * BN;
    const float* Xp = x + ((size_t)b * SEQ + (size_t)mt * BM) * IN_DIM;
    float* Op = out + ((size_t)b * SEQ + (size_t)mt * BM) * OUT_DIM + (size_t)nt * BN;

    f32x4 acc[8][4] = {};               // wave tile 128(m) x 64(n)

    const int mbase = (w >> 2) * 128;
    const int nbase = (w & 3) * 64;
    const int lrow  = lane & 15;
    const int lhi   = lane >> 4;

    // 2-deep staging sets, ALL indices compile-time (rule #20)
    f32x4 ra[2][4];
    f32x4 rb0[2][2], rb1[2][2];

    auto LOADT = [&](int ks, auto S) {
        constexpr int ss = decltype(S)::value;
        const float* Xk = Xp + ks * BK;
        #pragma unroll
        for (int i = 0; i < 4; ++i) {
            int f   = i * 512 + t;
            int row = f >> 3;
            int c4  = f & 7;
            ra[ss][i] = *reinterpret_cast<const f32x4*>(Xk + (size_t)row * IN_DIM + c4 * 4);
        }
        const float* Wk = Wp + (size_t)(ks * BK) * OUT_DIM;
        #pragma unroll
        for (int i = 0; i < 2; ++i) {
            int u  = i * 512 + t;
            int kp = u >> 6;
            int n4 = u & 63;
            const float* bse = Wk + (size_t)(2 * kp) * OUT_DIM + n4 * 4;
            rb0[ss][i] = *reinterpret_cast<const f32x4*>(bse);
            rb1[ss][i] = *reinterpret_cast<const f32x4*>(bse + OUT_DIM);
        }
    };

    // pack set ss -> LDS buffer ss (tile parity == buffer parity == set parity)
    auto STORET = [&](auto S) {
        constexpr int ss = decltype(S)::value;
        char* AsB = reinterpret_cast<char*>(&As[ss][0]);
        #pragma unroll
        for (int i = 0; i < 4; ++i) {
            int f   = i * 512 + t;
            int row = f >> 3;
            int c4  = f & 7;
            u32x2 q;
            q.x = pack2(ra[ss][i].x, ra[ss][i].y);
            q.y = pack2(ra[ss][i].z, ra[ss][i].w);
            *reinterpret_cast<u32x2*>(AsB + row * (LDA * 2) + c4 * 8) = q;
        }
        unsigned int* BsW = &Bs[ss][0];
        #pragma unroll
        for (int i = 0; i < 2; ++i) {
            int u  = i * 512 + t;
            int kp = u >> 6;
            int n4 = u & 63;
            u32x4 q;
            #pragma unroll
            for (int jj = 0; jj < 4; ++jj)
                q[jj] = pack2(rb0[ss][i][jj], rb1[ss][i][jj]);
            *reinterpret_cast<u32x4*>(BsW + kp * LDBW + n4 * 4) = q;
        }
    };

    auto COMPUTE = [&](auto S) {
        constexpr int ss = decltype(S)::value;
        const char* AsB = reinterpret_cast<const char*>(&As[ss][0]);
        const unsigned int* BsW = &Bs[ss][0];
        bf16x8 bfr[4];
        #pragma unroll
        for (int ni = 0; ni < 4; ++ni) {
            int n   = nbase + ni * 16 + lrow;
            int kp0 = lhi * 4;
            u32x4 wds;
            #pragma unroll
            for (int jj = 0; jj < 4; ++jj)
                wds[jj] = BsW[(kp0 + jj) * LDBW + n];
            bfr[ni] = __builtin_bit_cast(bf16x8, wds);
        }
        #pragma unroll
        for (int mi = 0; mi < 8; ++mi) {
            int r = mbase + mi * 16 + lrow;
            bf16x8 afr = *reinterpret_cast<const bf16x8*>(AsB + r * (LDA * 2) + lhi * 16);
            #pragma unroll
            for (int ni = 0; ni < 4; ++ni)
                acc[mi][ni] = __builtin_amdgcn_mfma_f32_16x16x32_bf16(
                    afr, bfr[ni], acc[mi][ni], 0, 0, 0);
        }
    };

    constexpr std::integral_constant<int, 0> S0{};
    constexpr std::integral_constant<int, 1> S1{};

    // prologue: tile0 -> buf0; tile1 loads in flight
    LOADT(0, S0);
    STORET(S0);
    LOADT(1, S1);
    asm volatile("s_waitcnt lgkmcnt(0)" ::: "memory");
    __builtin_amdgcn_s_barrier();

    // one barrier region per K-step: COMPUTE(p) overlaps STORET(p^1) + LOADT issue.
    // Safety: the single lgkmcnt(0) before each barrier drains this region's
    // ds_reads of buf p AND ds_writes of buf p^1; the next region's writes to
    // buf p are therefore ordered after all reads of buf p.
    for (int ks = 0; ks < NSTEP; ks += 2) {
        // even region: compute tile ks (buf0), stage tile ks+1 (set1 -> buf1)
        COMPUTE(S0);
        STORET(S1);                               // vmcnt-counted waits (1 step old)
        if (ks + 2 < NSTEP) LOADT(ks + 2, S0);    // refill set0, flies across barrier
        asm volatile("s_waitcnt lgkmcnt(0)" ::: "memory");
        __builtin_amdgcn_s_barrier();

        // odd region: compute tile ks+1 (buf1), stage tile ks+2 (set0 -> buf0)
        COMPUTE(S1);
        if (ks + 2 < NSTEP) STORET(S0);
        if (ks + 3 < NSTEP) LOADT(ks + 3, S1);
        if (ks + 2 < NSTEP) {
            asm volatile("s_waitcnt lgkmcnt(0)" ::: "memory");
            __builtin_amdgcn_s_barrier();
        }
    }

    // epilogue: C/D layout col=lane&15, row=(lane>>4)*4+reg
    const int lcol  = lane & 15;
    const int lrow4 = (lane >> 4) * 4;
    float bv[4];
    #pragma unroll
    for (int ni = 0; ni < 4; ++ni)
        bv[ni] = bias[(size_t)c * OUT_DIM + nt * BN + nbase + ni * 16 + lcol];

    #pragma unroll
    for (int mi = 0; mi < 8; ++mi) {
        int rbase = mbase + mi * 16 + lrow4;
        #pragma unroll
        for (int ni = 0; ni < 4; ++ni) {
            int ncol = nbase + ni * 16 + lcol;
            #pragma unroll
            for (int r = 0; r < 4; ++r) {
                Op[(size_t)(rbase + r) * OUT_DIM + ncol] = acc[mi][ni][r] + bv[ni];
            }
        }
    }
}

extern "C" void kernel_launch(void* const* d_in, const int* in_sizes, int n_in,
                              void* d_out, int out_size, void* d_ws, size_t ws_size,
                              hipStream_t stream) {
    const float* x      = (const float*)d_in[0];
    const int*   cid    = (const int*)d_in[1];
    const float* weight = (const float*)d_in[2];
    const float* bias   = (const float*)d_in[3];
    float* out = (float*)d_out;

    dim3 grid(256);     // flat: XCD-aware remap inside kernel; 1 block/CU
    dim3 block(512);
    hipLaunchKernelGGL(cslinear_kernel, grid, block, 0, stream,
                       x, cid, weight, bias, out);
}

// Round 9
// 51.045 us; speedup vs baseline: 1.1802x; 1.1366x over previous
//
#include <hip/hip_runtime.h>
#include <type_traits>

#define NUM_CATEGORIES 64
#define IN_DIM 1024
#define OUT_DIM 1024
#define BATCH 32
#define SEQ 512

#define BM 256
#define BN 256
#define BK 32
#define NSTEP (IN_DIM / BK)   // 32

#define LDA 40     // bf16 elems per A row (64B data + 16B pad)
#define LDBW 260   // u32 words per B k-pair row (256 data + 4 pad)

typedef float f32x4 __attribute__((ext_vector_type(4)));
typedef float f32x2 __attribute__((ext_vector_type(2)));
typedef unsigned int u32x4 __attribute__((ext_vector_type(4)));
typedef __bf16 bf16x2 __attribute__((ext_vector_type(2)));
typedef __bf16 bf16x4 __attribute__((ext_vector_type(4)));
typedef __bf16 bf16x8 __attribute__((ext_vector_type(8)));

__global__ __launch_bounds__(512, 2)
void cslinear_kernel(const float* __restrict__ x,
                     const int* __restrict__ cid,
                     const float* __restrict__ weight,
                     const float* __restrict__ bias,
                     float* __restrict__ out) {
    __shared__ unsigned short As[2][BM * LDA];          // 2 x 20 KB
    __shared__ unsigned int   Bs[2][(BK / 2) * LDBW];   // 2 x 16.25 KB

    const int t    = threadIdx.x;
    const int lane = t & 63;
    const int w    = t >> 6;      // 0..7

    // XCD-aware remap: slot s -> XCD s%8; each XCD owns 4 whole batches.
    const int s    = blockIdx.x;      // 0..255
    const int xcd  = s & 7;
    const int ixd  = s >> 3;          // 0..31
    const int b    = xcd + 8 * (ixd >> 3);
    const int j    = ixd & 7;
    const int nt   = j & 3;           // 0..3
    const int mt   = j >> 2;          // 0..1

    const int c = cid[b];
    const float* Wp = weight + (size_t)c * IN_DIM * OUT_DIM + (size_t)nt * BN;
    const float* Xp = x + ((size_t)b * SEQ + (size_t)mt * BM) * IN_DIM;
    float* Op = out + ((size_t)b * SEQ + (size_t)mt * BM) * OUT_DIM + (size_t)nt * BN;

    f32x4 acc[8][4] = {};               // wave tile 128(m) x 64(n)

    const int mbase = (w >> 2) * 128;
    const int nbase = (w & 3) * 64;
    const int lrow  = lane & 15;
    const int lhi   = lane >> 4;

    // 2-deep staging sets, ALL indices compile-time (rule #20)
    f32x4 ra[2][4];
    f32x4 rb0[2][2], rb1[2][2];

    auto LOADT = [&](int ks, auto S) {
        constexpr int ss = decltype(S)::value;
        const float* Xk = Xp + ks * BK;
        #pragma unroll
        for (int i = 0; i < 4; ++i) {
            int f   = i * 512 + t;
            int row = f >> 3;
            int c4  = f & 7;
            ra[ss][i] = *reinterpret_cast<const f32x4*>(Xk + (size_t)row * IN_DIM + c4 * 4);
        }
        const float* Wk = Wp + (size_t)(ks * BK) * OUT_DIM;
        #pragma unroll
        for (int i = 0; i < 2; ++i) {
            int u  = i * 512 + t;
            int kp = u >> 6;
            int n4 = u & 63;
            const float* bse = Wk + (size_t)(2 * kp) * OUT_DIM + n4 * 4;
            rb0[ss][i] = *reinterpret_cast<const f32x4*>(bse);
            rb1[ss][i] = *reinterpret_cast<const f32x4*>(bse + OUT_DIM);
        }
    };

    // pack set ss -> LDS buffer ss. Native casts -> compiler emits
    // v_cvt_pk_bf16_f32 (1 instr / f32-pair, RNE) instead of ~10 int-VALU ops
    // of the old hand-written round-to-nearest-even (R8's critical-path hog).
    auto STORET = [&](auto S) {
        constexpr int ss = decltype(S)::value;
        char* AsB = reinterpret_cast<char*>(&As[ss][0]);
        #pragma unroll
        for (int i = 0; i < 4; ++i) {
            int f   = i * 512 + t;
            int row = f >> 3;
            int c4  = f & 7;
            bf16x4 a4 = __builtin_convertvector(ra[ss][i], bf16x4);
            *reinterpret_cast<bf16x4*>(AsB + row * (LDA * 2) + c4 * 8) = a4;
        }
        unsigned int* BsW = &Bs[ss][0];
        #pragma unroll
        for (int i = 0; i < 2; ++i) {
            int u  = i * 512 + t;
            int kp = u >> 6;
            int n4 = u & 63;
            u32x4 q;
            #pragma unroll
            for (int jj = 0; jj < 4; ++jj) {
                f32x2 pr;
                pr.x = rb0[ss][i][jj];   // k   (low 16)
                pr.y = rb1[ss][i][jj];   // k+1 (high 16)
                bf16x2 pb = __builtin_convertvector(pr, bf16x2);
                q[jj] = __builtin_bit_cast(unsigned int, pb);
            }
            *reinterpret_cast<u32x4*>(BsW + kp * LDBW + n4 * 4) = q;
        }
    };

    auto COMPUTE = [&](auto S) {
        constexpr int ss = decltype(S)::value;
        const char* AsB = reinterpret_cast<const char*>(&As[ss][0]);
        const unsigned int* BsW = &Bs[ss][0];
        bf16x8 bfr[4];
        #pragma unroll
        for (int ni = 0; ni < 4; ++ni) {
            int n   = nbase + ni * 16 + lrow;
            int kp0 = lhi * 4;
            u32x4 wds;
            #pragma unroll
            for (int jj = 0; jj < 4; ++jj)
                wds[jj] = BsW[(kp0 + jj) * LDBW + n];
            bfr[ni] = __builtin_bit_cast(bf16x8, wds);
        }
        #pragma unroll
        for (int mi = 0; mi < 8; ++mi) {
            int r = mbase + mi * 16 + lrow;
            bf16x8 afr = *reinterpret_cast<const bf16x8*>(AsB + r * (LDA * 2) + lhi * 16);
            #pragma unroll
            for (int ni = 0; ni < 4; ++ni)
                acc[mi][ni] = __builtin_amdgcn_mfma_f32_16x16x32_bf16(
                    afr, bfr[ni], acc[mi][ni], 0, 0, 0);
        }
    };

    constexpr std::integral_constant<int, 0> S0{};
    constexpr std::integral_constant<int, 1> S1{};

    // prologue: tile0 -> buf0; tile1 loads in flight
    LOADT(0, S0);
    STORET(S0);
    LOADT(1, S1);
    asm volatile("s_waitcnt lgkmcnt(0)" ::: "memory");
    __builtin_amdgcn_s_barrier();

    // one barrier region per K-step: COMPUTE(p) overlaps STORET(p^1) + LOADT issue.
    // Safety: the single lgkmcnt(0) before each barrier drains this region's
    // ds_reads of buf p AND ds_writes of buf p^1; the next region's writes to
    // buf p are therefore ordered after all reads of buf p.
    for (int ks = 0; ks < NSTEP; ks += 2) {
        // even region: compute tile ks (buf0), stage tile ks+1 (set1 -> buf1)
        COMPUTE(S0);
        STORET(S1);                               // vmcnt-counted waits (1 step old)
        if (ks + 2 < NSTEP) LOADT(ks + 2, S0);    // refill set0, flies across barrier
        asm volatile("s_waitcnt lgkmcnt(0)" ::: "memory");
        __builtin_amdgcn_s_barrier();

        // odd region: compute tile ks+1 (buf1), stage tile ks+2 (set0 -> buf0)
        COMPUTE(S1);
        if (ks + 2 < NSTEP) STORET(S0);
        if (ks + 3 < NSTEP) LOADT(ks + 3, S1);
        if (ks + 2 < NSTEP) {
            asm volatile("s_waitcnt lgkmcnt(0)" ::: "memory");
            __builtin_amdgcn_s_barrier();
        }
    }

    // epilogue: C/D layout col=lane&15, row=(lane>>4)*4+reg
    const int lcol  = lane & 15;
    const int lrow4 = (lane >> 4) * 4;
    float bv[4];
    #pragma unroll
    for (int ni = 0; ni < 4; ++ni)
        bv[ni] = bias[(size_t)c * OUT_DIM + nt * BN + nbase + ni * 16 + lcol];

    #pragma unroll
    for (int mi = 0; mi < 8; ++mi) {
        int rbase = mbase + mi * 16 + lrow4;
        #pragma unroll
        for (int ni = 0; ni < 4; ++ni) {
            int ncol = nbase + ni * 16 + lcol;
            #pragma unroll
            for (int r = 0; r < 4; ++r) {
                Op[(size_t)(rbase + r) * OUT_DIM + ncol] = acc[mi][ni][r] + bv[ni];
            }
        }
    }
}

extern "C" void kernel_launch(void* const* d_in, const int* in_sizes, int n_in,
                              void* d_out, int out_size, void* d_ws, size_t ws_size,
                              hipStream_t stream) {
    const float* x      = (const float*)d_in[0];
    const int*   cid    = (const int*)d_in[1];
    const float* weight = (const float*)d_in[2];
    const float* bias   = (const float*)d_in[3];
    float* out = (float*)d_out;

    dim3 grid(256);     // flat: XCD-aware remap inside kernel; 1 block/CU
    dim3 block(512);
    hipLaunchKernelGGL(cslinear_kernel, grid, block, 0, stream,
                       x, cid, weight, bias, out);
}